// Round 7
// baseline (3186.702 us; speedup 1.0000x reference)
//
#include <hip/hip_runtime.h>

// ---------------------------------------------------------------------------
// 2-branch LSTM-CTC transcriber for MI355X.  B=32, T=1024, F=40, H=256.
//
// Round-4 changes vs round-3:
//  * REVERT round-3 PINs (regressed; weights already live in unified
//    VGPR/AGPR file — VGPR_Count=112 reports only the VGPR half).
//  * Tag-in-mantissa sync protocol: publish h with the step tag embedded in
//    the low 8 mantissa bits of every dword (masked off by consumers before
//    use; ~2^-16 relative truncation, deterministic). Consumers poll the h
//    data itself and accept when all 32 tags match. Removes BOTH the
//    producer-side s_waitcnt vmcnt(0) (store-ack round trip) and the
//    separate flag store + flag-poll round trip: 2 fewer serial L3 RTs/step.
//  * part[] LDS double-buffered by step parity -> second __syncthreads
//    removed (waves no longer wait for rg0's gate math each step).
// ---------------------------------------------------------------------------

#define HID 256
#define TT  1024
#define TP  342
#define FF  40

typedef float f32x4 __attribute__((ext_vector_type(4)));

__device__ __forceinline__ float sigf(float x)     { return 1.0f / (1.0f + __expf(-x)); }
__device__ __forceinline__ float tanhfast(float x) { return 1.0f - 2.0f / (__expf(2.0f * x) + 1.0f); }

// device-coherent (sc0 sc1) primitives -------------------------------------
__device__ __forceinline__ void coh_store_u32(unsigned* p, unsigned v) {
    asm volatile("global_store_dword %0, %1, off sc0 sc1"
                 :: "v"(p), "v"(v) : "memory");
}
// load 32 consecutive floats (8 x dwordx4), device-coherent, one waitcnt
__device__ __forceinline__ void coh_load_h32(const float* p, f32x4 (&a)[8]) {
    asm volatile(
        "global_load_dwordx4 %0, %8, off sc0 sc1\n\t"
        "global_load_dwordx4 %1, %8, off offset:16 sc0 sc1\n\t"
        "global_load_dwordx4 %2, %8, off offset:32 sc0 sc1\n\t"
        "global_load_dwordx4 %3, %8, off offset:48 sc0 sc1\n\t"
        "global_load_dwordx4 %4, %8, off offset:64 sc0 sc1\n\t"
        "global_load_dwordx4 %5, %8, off offset:80 sc0 sc1\n\t"
        "global_load_dwordx4 %6, %8, off offset:96 sc0 sc1\n\t"
        "global_load_dwordx4 %7, %8, off offset:112 sc0 sc1\n\t"
        "s_waitcnt vmcnt(0)"
        : "=&v"(a[0]), "=&v"(a[1]), "=&v"(a[2]), "=&v"(a[3]),
          "=&v"(a[4]), "=&v"(a[5]), "=&v"(a[6]), "=&v"(a[7])
        : "v"(p) : "memory");
}
// poll until all 32 dwords carry `tag` in their low byte
__device__ __forceinline__ void poll_h32(const float* p, unsigned tag, f32x4 (&hv)[8]) {
    unsigned m;
    do {
        coh_load_h32(p, hv);
        m = 0;
#pragma unroll
        for (int i = 0; i < 8; ++i)
#pragma unroll
            for (int j = 0; j < 4; ++j)
                m |= (__float_as_uint(hv[i][j]) ^ tag);
    } while (m & 0xFFu);
}
__device__ __forceinline__ float untag(float v) {
    return __uint_as_float(__float_as_uint(v) & 0xFFFFFF00u);
}

// ---------------- LSTM layer 1 (input = clipped x, fused maxpool) ----------
__global__ __launch_bounds__(512, 2) void lstm1_kernel(
    const float* __restrict__ x, const int* __restrict__ x_len,
    const float* __restrict__ Wk_s, const float* __restrict__ Wr_s, const float* __restrict__ b_s,
    const float* __restrict__ Wk_c, const float* __restrict__ Wr_c, const float* __restrict__ b_c,
    float* __restrict__ hbuf,          // [2][64][256] (zeroed -> h=0, tag=0)
    float* __restrict__ pooled)        // [2][32][342][256]
{
    const int blk = blockIdx.x;        // 0..255
    const int q   = blk >> 6;          // quarter 0..3
    const int grp = blk & 63;          // (branch, sample)
    const int br  = grp >> 5;
    const int s   = grp & 31;
    const int tid = threadIdx.x;
    const int u   = tid & 63;          // unit within quarter
    const int rg  = tid >> 6;          // row-group 0..7 (32 h-rows each)
    const int col0 = q * 64 + u;       // output unit index within H

    const float* Wk = br ? Wk_c : Wk_s;
    const float* Wr = br ? Wr_c : Wr_s;
    const float* bb = br ? b_c  : b_s;

    // Recurrent weight slice: w[g][k] = Wr[rg*32+k][g*256+col0]
    float w[4][32];
#pragma unroll
    for (int g = 0; g < 4; ++g)
#pragma unroll
        for (int k = 0; k < 32; ++k)
            w[g][k] = Wr[(size_t)(rg * 32 + k) * 1024 + g * 256 + col0];

    // Input-kernel slice: rows rg*8..rg*8+7 (rg<5 covers F=40)
    float wk[4][8];
    if (rg < 5) {
#pragma unroll
        for (int g = 0; g < 4; ++g)
#pragma unroll
            for (int j = 0; j < 8; ++j)
                wk[g][j] = Wk[(size_t)(rg * 8 + j) * 1024 + g * 256 + col0];
    }

    float bias[4] = {0.f, 0.f, 0.f, 0.f};
    if (rg == 0) {
#pragma unroll
        for (int g = 0; g < 4; ++g) bias[g] = bb[g * 256 + col0];
    }

    const int len = x_len[s];
    float cst = 0.f, hcur = 0.f, pm = -1e30f;

    __shared__ float part[2][8][4][64];   // step-parity double buffer

    for (int t = 0; t < TT; ++t) {
        if (t < len) {
            // 1) independent input contribution (off critical path)
            float acc[4] = {0.f, 0.f, 0.f, 0.f};
            if (rg < 5) {
                const float* xr = x + ((size_t)s * TT + t) * FF + rg * 8;
#pragma unroll
                for (int j = 0; j < 8; ++j) {
                    float v = xr[j];
                    v = fminf(fmaxf(v, -3.f), 3.f);   // clip(x,-3,3)
#pragma unroll
                    for (int g = 0; g < 4; ++g) acc[g] += v * wk[g][j];
                }
            }
            // 2) poll my 32 h rows of step t (tag = t&0xFF rides in the data)
            const float* hr = hbuf + ((size_t)(t & 1) * 64 + grp) * 256 + rg * 32;
            f32x4 hv[8];
            poll_h32(hr, (unsigned)t & 0xFFu, hv);

            // 3) partial z for my rows (mask tag bits off before use)
#pragma unroll
            for (int i = 0; i < 8; ++i) {
#pragma unroll
                for (int jj = 0; jj < 4; ++jj) {
                    float hh = untag(hv[i][jj]);
#pragma unroll
                    for (int g = 0; g < 4; ++g)
                        acc[g] += hh * w[g][i * 4 + jj];
                }
            }
#pragma unroll
            for (int g = 0; g < 4; ++g) part[t & 1][rg][g][u] = acc[g];
            __syncthreads();

            // 4) gate math + publish h quarter (wave rg==0 only)
            if (rg == 0) {
                float z[4];
#pragma unroll
                for (int g = 0; g < 4; ++g) {
                    float sum = bias[g];
#pragma unroll
                    for (int r = 0; r < 8; ++r) sum += part[t & 1][r][g][u];
                    z[g] = sum;
                }
                float ig = sigf(z[0]);
                float fg = sigf(z[1]);
                float gg = tanhfast(z[2]);
                float og = sigf(z[3]);
                cst  = fg * cst + ig * gg;
                hcur = og * tanhfast(cst);
                float* hw = hbuf + ((size_t)((t + 1) & 1) * 64 + grp) * 256;
                unsigned hb = (__float_as_uint(hcur) & 0xFFFFFF00u)
                            | ((unsigned)(t + 1) & 0xFFu);
                coh_store_u32((unsigned*)(hw + col0), hb);   // no wait, no flag
            }
            // no second __syncthreads: part[] is parity double-buffered
        }
        // fused maxpool3 stride3 SAME: window t' covers t in {3t'-1, 3t', 3t'+1}
        if (rg == 0) {
            pm = fmaxf(pm, hcur);
            if ((t % 3) == 1) {
                int tp = (t - 1) / 3;
                pooled[(((size_t)br * 32 + s) * TP + tp) * HID + col0] = pm;
                pm = -1e30f;
            }
        }
    }
    if (rg == 0)   // final window t'=341 covers t=1022,1023
        pooled[(((size_t)br * 32 + s) * TP + 341) * HID + col0] = pm;
}

// ---------------- LSTM layers 2/3 (input projection precomputed) -----------
__global__ __launch_bounds__(512, 2) void lstm23_kernel(
    const float* __restrict__ xz,      // [2][32][342][1024] (bias folded in)
    const int* __restrict__ x_len,
    const float* __restrict__ Wr_s, const float* __restrict__ Wr_c,
    float* __restrict__ hbuf,
    float* __restrict__ yout)          // [2][32][342][256]
{
    const int blk = blockIdx.x;
    const int q   = blk >> 6;
    const int grp = blk & 63;
    const int br  = grp >> 5;
    const int s   = grp & 31;
    const int tid = threadIdx.x;
    const int u   = tid & 63;
    const int rg  = tid >> 6;
    const int col0 = q * 64 + u;

    const float* Wr = br ? Wr_c : Wr_s;

    float w[4][32];
#pragma unroll
    for (int g = 0; g < 4; ++g)
#pragma unroll
        for (int k = 0; k < 32; ++k)
            w[g][k] = Wr[(size_t)(rg * 32 + k) * 1024 + g * 256 + col0];

    const int len = (x_len[s] + 2) / 3;   // seq_len after pool
    float cst = 0.f, hcur = 0.f;

    __shared__ float part[2][8][4][64];

    for (int t = 0; t < TP; ++t) {
        const size_t row = ((size_t)br * 32 + s) * TP + t;
        if (t < len) {
            // independent input projection (rg==0 lanes) — issue before poll
            float xzv[4] = {0.f, 0.f, 0.f, 0.f};
            if (rg == 0) {
#pragma unroll
                for (int g = 0; g < 4; ++g)
                    xzv[g] = xz[row * 1024 + g * 256 + col0];
            }
            const float* hr = hbuf + ((size_t)(t & 1) * 64 + grp) * 256 + rg * 32;
            f32x4 hv[8];
            poll_h32(hr, (unsigned)t & 0xFFu, hv);

            float acc[4] = {0.f, 0.f, 0.f, 0.f};
#pragma unroll
            for (int i = 0; i < 8; ++i) {
#pragma unroll
                for (int jj = 0; jj < 4; ++jj) {
                    float hh = untag(hv[i][jj]);
#pragma unroll
                    for (int g = 0; g < 4; ++g)
                        acc[g] += hh * w[g][i * 4 + jj];
                }
            }
#pragma unroll
            for (int g = 0; g < 4; ++g) part[t & 1][rg][g][u] = acc[g];
            __syncthreads();

            if (rg == 0) {
                float z[4];
#pragma unroll
                for (int g = 0; g < 4; ++g) {
                    float sum = xzv[g];
#pragma unroll
                    for (int r = 0; r < 8; ++r) sum += part[t & 1][r][g][u];
                    z[g] = sum;
                }
                float ig = sigf(z[0]);
                float fg = sigf(z[1]);
                float gg = tanhfast(z[2]);
                float og = sigf(z[3]);
                cst  = fg * cst + ig * gg;
                hcur = og * tanhfast(cst);
                float* hw = hbuf + ((size_t)((t + 1) & 1) * 64 + grp) * 256;
                unsigned hb = (__float_as_uint(hcur) & 0xFFFFFF00u)
                            | ((unsigned)(t + 1) & 0xFFu);
                coh_store_u32((unsigned*)(hw + col0), hb);
            }
        }
        if (rg == 0)
            yout[row * HID + col0] = hcur;   // carried value when masked
    }
}

// ---------------- xz = A @ Wk + b (per-branch weights) ---------------------
// A: (21888, 256) rows 0..10943 branch s, 10944.. branch c. out: (21888, 1024)
__global__ __launch_bounds__(256) void gemm_xz(
    const float* __restrict__ A,
    const float* __restrict__ Ws, const float* __restrict__ Wc,
    const float* __restrict__ bs, const float* __restrict__ bc,
    float* __restrict__ out)
{
    __shared__ float As[32][68];    // [k][m], padded
    __shared__ float Bs[32][132];   // [k][n], padded
    const int tid = threadIdx.x;
    const int bx = blockIdx.x, by = blockIdx.y;   // 8 x 342
    const int row0 = by * 64, col0 = bx * 128;
    const int br = (by >= 171);
    const float* W    = br ? Wc : Ws;
    const float* bias = br ? bc : bs;
    const int tx = tid & 15, ty = tid >> 4;

    float acc[4][8];
#pragma unroll
    for (int i = 0; i < 4; ++i)
#pragma unroll
        for (int j = 0; j < 8; ++j) acc[i][j] = 0.f;

    for (int k0 = 0; k0 < 256; k0 += 32) {
#pragma unroll
        for (int i = 0; i < 2; ++i) {              // A tile 64x32, store transposed
            int c = tid * 2 + i;
            int r = c >> 3, kv = c & 7;
            float4 v = *(const float4*)(A + (size_t)(row0 + r) * 256 + k0 + kv * 4);
            As[kv * 4 + 0][r] = v.x; As[kv * 4 + 1][r] = v.y;
            As[kv * 4 + 2][r] = v.z; As[kv * 4 + 3][r] = v.w;
        }
#pragma unroll
        for (int i = 0; i < 4; ++i) {              // B tile 32x128
            int c = tid + i * 256;
            int kr = c >> 5, nv = c & 31;
            *(float4*)&Bs[kr][nv * 4] =
                *(const float4*)(W + (size_t)(k0 + kr) * 1024 + col0 + nv * 4);
        }
        __syncthreads();
#pragma unroll
        for (int k = 0; k < 32; ++k) {
            float4 a  = *(const float4*)&As[k][ty * 4];
            float4 b0 = *(const float4*)&Bs[k][tx * 8];
            float4 b1 = *(const float4*)&Bs[k][tx * 8 + 4];
            float av[4] = {a.x, a.y, a.z, a.w};
            float bv[8] = {b0.x, b0.y, b0.z, b0.w, b1.x, b1.y, b1.z, b1.w};
#pragma unroll
            for (int i = 0; i < 4; ++i)
#pragma unroll
                for (int j = 0; j < 8; ++j)
                    acc[i][j] += av[i] * bv[j];
        }
        __syncthreads();
    }
    float bv[8];
#pragma unroll
    for (int j = 0; j < 8; ++j) bv[j] = bias[col0 + tx * 8 + j];
#pragma unroll
    for (int i = 0; i < 4; ++i) {
        int r = row0 + ty * 4 + i;
        float4 o0 = {acc[i][0] + bv[0], acc[i][1] + bv[1], acc[i][2] + bv[2], acc[i][3] + bv[3]};
        float4 o1 = {acc[i][4] + bv[4], acc[i][5] + bv[5], acc[i][6] + bv[6], acc[i][7] + bv[7]};
        float* po = out + (size_t)r * 1024 + col0 + tx * 8;
        *(float4*)(po)     = o0;
        *(float4*)(po + 4) = o1;
    }
}

// ---------------- CTC projection -------------------------------------------
__global__ __launch_bounds__(256) void ctc_kernel(
    const float* __restrict__ Y,      // (21888, 256)
    const float* __restrict__ Wct,    // (256, 30)
    const float* __restrict__ bct,    // (30)
    float* __restrict__ dout)
{
    __shared__ float wl[256 * 30];
    __shared__ float yl[8][257];
    const int tid = threadIdx.x;
    const int row0 = blockIdx.x * 8;

    for (int i = tid; i < 7680; i += 256) wl[i] = Wct[i];
#pragma unroll
    for (int i = 0; i < 8; ++i) {
        int c = tid + i * 256;
        int r = c >> 8, k = c & 255;
        yl[r][k] = Y[(size_t)(row0 + r) * 256 + k];
    }
    __syncthreads();

    const int v = tid & 31, r = tid >> 5;
    if (v < 30) {
        float acc = bct[v];
#pragma unroll 8
        for (int k = 0; k < 256; ++k) acc += yl[r][k] * wl[k * 30 + v];
        int gr = row0 + r;
        int br = gr / 10944;
        int rr = gr - br * 10944;
        dout[(br ? 328352 : 0) + (size_t)rr * 30 + v] = acc;
    }
}

// ---------------- lens + close flags ----------------------------------------
__global__ __launch_bounds__(256) void finalize_kernel(
    const int* __restrict__ x_len, float* __restrict__ dout)
{
    const int b = blockIdx.x, tid = threadIdx.x;
    const float* cs = dout + (size_t)b * 10260;
    const float* cc = dout + 328352 + (size_t)b * 10260;
    __shared__ int flag;
    if (tid == 0) flag = 1;
    __syncthreads();
    bool ok = true;
    for (int i = tid; i < 10260; i += 256)
        ok &= (fabsf(cs[i] - cc[i]) < 1e-5f);
    if (!ok) atomicAnd(&flag, 0);
    __syncthreads();
    if (tid == 0) {
        float L = (float)((x_len[b] + 2) / 3);
        dout[328320 + b] = L;          // len_s
        dout[656672 + b] = L;          // len_c
        dout[656704 + b] = flag ? 1.0f : 0.0f;  // close
    }
}

// ---------------------------------------------------------------------------
extern "C" void kernel_launch(void* const* d_in, const int* in_sizes, int n_in,
                              void* d_out, int out_size, void* d_ws, size_t ws_size,
                              hipStream_t stream)
{
    (void)in_sizes; (void)n_in; (void)out_size;
    const float* x     = (const float*)d_in[0];
    const int*   x_len = (const int*)  d_in[1];
    const float* ws0_k = (const float*)d_in[2];
    const float* ws0_r = (const float*)d_in[3];
    const float* ws0_b = (const float*)d_in[4];
    const float* ws1_k = (const float*)d_in[5];
    const float* ws1_r = (const float*)d_in[6];
    const float* ws1_b = (const float*)d_in[7];
    const float* wc0_k = (const float*)d_in[8];
    const float* wc0_r = (const float*)d_in[9];
    const float* wc0_b = (const float*)d_in[10];
    const float* wc1_k = (const float*)d_in[11];
    const float* wc1_r = (const float*)d_in[12];
    const float* wc1_b = (const float*)d_in[13];
    const float* ctc_w = (const float*)d_in[14];
    const float* ctc_b = (const float*)d_in[15];
    float* out = (float*)d_out;
    char*  ws  = (char*)d_ws;

    // workspace layout
    const size_t h_bytes  = 3ull * 2 * 64 * 256 * sizeof(float);      // 393216
    const size_t off_b0   = h_bytes;
    const size_t b0_bytes = 2ull * 32 * 342 * 256 * sizeof(float);    // 22.4 MB (pooled/ys2/ys3)
    const size_t off_b1   = off_b0 + b0_bytes;
    const size_t b1_bytes = 2ull * 32 * 342 * 1024 * sizeof(float);   // 89.7 MB (xz)
    if (ws_size < off_b1 + b1_bytes) return;   // need ~112 MB

    float* h1 = (float*)ws;
    float* h2 = h1 + 2 * 64 * 256;
    float* h3 = h2 + 2 * 64 * 256;
    float* buf0 = (float*)(ws + off_b0);
    float* buf1 = (float*)(ws + off_b1);

    // zero h double-buffers (h=0, tag=0 for t=0) — fresh every launch/replay
    hipMemsetAsync(ws, 0, h_bytes, stream);

    // LSTM1 + fused maxpool -> buf0 = pooled
    lstm1_kernel<<<256, 512, 0, stream>>>(x, x_len, ws0_k, ws0_r, ws0_b,
                                          wc0_k, wc0_r, wc0_b, h1, buf0);
    // xz2 = pooled @ Wk1 + b1 -> buf1
    gemm_xz<<<dim3(8, 342), 256, 0, stream>>>(buf0, ws1_k, wc1_k, ws1_b, wc1_b, buf1);
    // LSTM2 -> buf0 = ys2
    lstm23_kernel<<<256, 512, 0, stream>>>(buf1, x_len, ws1_r, wc1_r, h2, buf0);
    // xz3 = ys2 @ Wk1 + b1 -> buf1
    gemm_xz<<<dim3(8, 342), 256, 0, stream>>>(buf0, ws1_k, wc1_k, ws1_b, wc1_b, buf1);
    // LSTM3 -> buf0 = ys3
    lstm23_kernel<<<256, 512, 0, stream>>>(buf1, x_len, ws1_r, wc1_r, h3, buf0);
    // CTC projection -> d_out ctc regions
    ctc_kernel<<<2736, 256, 0, stream>>>(buf0, ctc_w, ctc_b, out);
    // lens + close
    finalize_kernel<<<32, 256, 0, stream>>>(x_len, out);
}

// Round 9
// 2305.457 us; speedup vs baseline: 1.3822x; 1.3822x over previous
//
#include <hip/hip_runtime.h>

// ---------------------------------------------------------------------------
// 2-branch LSTM-CTC transcriber for MI355X.  B=32, T=1024, F=40, H=256.
//
// Round-9 changes vs round-8:
//  * REVERT round-8 XCD-L2 fast path (hung: hwreg-based "same XCD" check can
//    report false-same; sc0-only cross-XCD polling then spins on a stale L2
//    line forever). All cross-wg traffic is LLC-coherent (sc0 sc1) again.
//  * Single-poller: only wave rg==0 polls h — and only the 3 REMOTE quarters
//    (own quarter comes from its hcur registers). It untags and broadcasts h
//    into LDS; the other 7 waves read h from LDS. ~10x less LLC poll traffic,
//    one discovery chain instead of max-of-8, untag moved off the FMA loop.
//  * 2-deep software-pipelined poll (inline asm, alternating reg sets,
//    s_waitcnt vmcnt(3)): discovery ~= half a poll RT after visibility.
//    Tag monotonicity makes "use any load issued after the witnessing load"
//    safe; the y-success path explicitly moves y->x.
//  * part[] parity dropped; two intra-wg barriers per step (race-free: wave0
//    only reaches its reduce after barrier2, writers only write after
//    barrier1 which wave0 joins after the reduce).
// ---------------------------------------------------------------------------

#define HID 256
#define TT  1024
#define TP  342
#define FF  40

typedef float f32x4 __attribute__((ext_vector_type(4)));

__device__ __forceinline__ float sigf(float x)     { return 1.0f / (1.0f + __expf(-x)); }
__device__ __forceinline__ float tanhfast(float x) { return 1.0f - 2.0f / (__expf(2.0f * x) + 1.0f); }

__device__ __forceinline__ void coh_store_u32(unsigned* p, unsigned v) {
    asm volatile("global_store_dword %0, %1, off sc0 sc1"
                 :: "v"(p), "v"(v) : "memory");
}
__device__ __forceinline__ float untag(float v) {
    return __uint_as_float(__float_as_uint(v) & 0xFFFFFF00u);
}

// 2-deep pipelined poll on three lane-addressed dwords (LLC-coherent).
// Returns once all lanes observe `tag` in the low byte of all three dwords.
// Monotone buffers (each dword written once per step epoch) make the x-return
// on the x-success path safe; y-success copies y->x after draining.
__device__ __forceinline__ void poll3(const float* p0, const float* p1, const float* p2,
                                      unsigned tag, float& r0, float& r1, float& r2) {
    float x0, x1, x2, y0, y1, y2;
    unsigned t0, t1;
    asm volatile(
        "global_load_dword %[x0], %[p0], off sc0 sc1\n\t"
        "global_load_dword %[x1], %[p1], off sc0 sc1\n\t"
        "global_load_dword %[x2], %[p2], off sc0 sc1\n\t"
        "1:\n\t"
        "global_load_dword %[y0], %[p0], off sc0 sc1\n\t"
        "global_load_dword %[y1], %[p1], off sc0 sc1\n\t"
        "global_load_dword %[y2], %[p2], off sc0 sc1\n\t"
        "s_waitcnt vmcnt(3)\n\t"
        "v_xor_b32 %[t0], %[x0], %[tag]\n\t"
        "v_xor_b32 %[t1], %[x1], %[tag]\n\t"
        "v_or_b32 %[t0], %[t0], %[t1]\n\t"
        "v_xor_b32 %[t1], %[x2], %[tag]\n\t"
        "v_or_b32 %[t0], %[t0], %[t1]\n\t"
        "v_and_b32 %[t0], 0xff, %[t0]\n\t"
        "v_cmp_ne_u32 vcc, 0, %[t0]\n\t"
        "s_cbranch_vccz 2f\n\t"                // x matched on all lanes
        "global_load_dword %[x0], %[p0], off sc0 sc1\n\t"
        "global_load_dword %[x1], %[p1], off sc0 sc1\n\t"
        "global_load_dword %[x2], %[p2], off sc0 sc1\n\t"
        "s_waitcnt vmcnt(3)\n\t"
        "v_xor_b32 %[t0], %[y0], %[tag]\n\t"
        "v_xor_b32 %[t1], %[y1], %[tag]\n\t"
        "v_or_b32 %[t0], %[t0], %[t1]\n\t"
        "v_xor_b32 %[t1], %[y2], %[tag]\n\t"
        "v_or_b32 %[t0], %[t0], %[t1]\n\t"
        "v_and_b32 %[t0], 0xff, %[t0]\n\t"
        "v_cmp_ne_u32 vcc, 0, %[t0]\n\t"
        "s_cbranch_vccnz 1b\n\t"
        "s_waitcnt vmcnt(0)\n\t"               // y matched: drain x-in-flight
        "v_mov_b32 %[x0], %[y0]\n\t"           // and return y's witnessed data
        "v_mov_b32 %[x1], %[y1]\n\t"
        "v_mov_b32 %[x2], %[y2]\n\t"
        "s_branch 3f\n\t"
        "2:\n\t"
        "s_waitcnt vmcnt(0)\n\t"               // drain in-flight y (discarded)
        "3:\n\t"
        : [x0]"=&v"(x0), [x1]"=&v"(x1), [x2]"=&v"(x2),
          [y0]"=&v"(y0), [y1]"=&v"(y1), [y2]"=&v"(y2),
          [t0]"=&v"(t0), [t1]"=&v"(t1)
        : [p0]"v"(p0), [p1]"v"(p1), [p2]"v"(p2), [tag]"v"(tag)
        : "vcc", "memory");
    r0 = x0; r1 = x1; r2 = x2;
}

// ---------------- LSTM layer 1 (input = clipped x, fused maxpool) ----------
__global__ __launch_bounds__(512, 2) void lstm1_kernel(
    const float* __restrict__ x, const int* __restrict__ x_len,
    const float* __restrict__ Wk_s, const float* __restrict__ Wr_s, const float* __restrict__ b_s,
    const float* __restrict__ Wk_c, const float* __restrict__ Wr_c, const float* __restrict__ b_c,
    float* __restrict__ hbuf,          // [2][64][256] (zeroed -> h=0, tag=0)
    float* __restrict__ pooled)        // [2][32][342][256]
{
    const int blk = blockIdx.x;        // 0..255
    const int q   = blk >> 6;          // quarter 0..3
    const int grp = blk & 63;          // (branch, sample)
    const int br  = grp >> 5;
    const int s   = grp & 31;
    const int tid = threadIdx.x;
    const int u   = tid & 63;          // unit within quarter
    const int rg  = tid >> 6;          // row-group 0..7 (32 h-rows each)
    const int col0 = q * 64 + u;       // output unit index within H

    const float* Wk = br ? Wk_c : Wk_s;
    const float* Wr = br ? Wr_c : Wr_s;
    const float* bb = br ? b_c  : b_s;

    // Recurrent weight slice: w[g][k] = Wr[rg*32+k][g*256+col0]
    float w[4][32];
#pragma unroll
    for (int g = 0; g < 4; ++g)
#pragma unroll
        for (int k = 0; k < 32; ++k)
            w[g][k] = Wr[(size_t)(rg * 32 + k) * 1024 + g * 256 + col0];

    // Input-kernel slice moved to waves 3..7 (wave0 is the poller):
    // wave rg in [3,8) handles x rows (rg-3)*8 .. +8
    float wk[4][8];
    if (rg >= 3) {
#pragma unroll
        for (int g = 0; g < 4; ++g)
#pragma unroll
            for (int j = 0; j < 8; ++j)
                wk[g][j] = Wk[(size_t)((rg - 3) * 8 + j) * 1024 + g * 256 + col0];
    }

    float bias[4] = {0.f, 0.f, 0.f, 0.f};
    if (rg == 0) {
#pragma unroll
        for (int g = 0; g < 4; ++g) bias[g] = bb[g * 256 + col0];
    }

    const int len = x_len[s];
    float cst = 0.f, hcur = 0.f, pm = -1e30f;

    __shared__ float h_lds[256];
    __shared__ float part[8][4][64];

    const int q1 = (q + 1) & 3, q2 = (q + 2) & 3, q3 = (q + 3) & 3;

    for (int t = 0; t < TT; ++t) {
        if (t < len) {
            // ---- phase 1: wave0 polls remote quarters, broadcasts via LDS;
            //      waves 3..7 compute the x contribution meanwhile.
            float acc[4] = {0.f, 0.f, 0.f, 0.f};
            if (rg >= 3) {
                const float* xr = x + ((size_t)s * TT + t) * FF + (rg - 3) * 8;
#pragma unroll
                for (int j = 0; j < 8; ++j) {
                    float v = xr[j];
                    v = fminf(fmaxf(v, -3.f), 3.f);   // clip(x,-3,3)
#pragma unroll
                    for (int g = 0; g < 4; ++g) acc[g] += v * wk[g][j];
                }
            }
            if (rg == 0) {
                const float* hb = hbuf + ((size_t)(t & 1) * 64 + grp) * 256;
                float r0, r1, r2;
                poll3(hb + q1 * 64 + u, hb + q2 * 64 + u, hb + q3 * 64 + u,
                      (unsigned)t & 0xFFu, r0, r1, r2);
                h_lds[q1 * 64 + u] = untag(r0);
                h_lds[q2 * 64 + u] = untag(r1);
                h_lds[q3 * 64 + u] = untag(r2);
                h_lds[q  * 64 + u] = hcur;            // own quarter from regs
            }
            __syncthreads();                          // h_lds ready

            // ---- phase 2: all waves FMA from LDS h
            f32x4 hv[8];
            const f32x4* hp = (const f32x4*)&h_lds[rg * 32];
#pragma unroll
            for (int i = 0; i < 8; ++i) hv[i] = hp[i];
#pragma unroll
            for (int i = 0; i < 8; ++i) {
#pragma unroll
                for (int jj = 0; jj < 4; ++jj) {
                    float hh = hv[i][jj];
#pragma unroll
                    for (int g = 0; g < 4; ++g)
                        acc[g] += hh * w[g][i * 4 + jj];
                }
            }
#pragma unroll
            for (int g = 0; g < 4; ++g) part[rg][g][u] = acc[g];
            __syncthreads();                          // parts ready

            // ---- phase 3: wave0 reduce + gates + publish
            if (rg == 0) {
                float z[4];
#pragma unroll
                for (int g = 0; g < 4; ++g) {
                    float sum = bias[g];
#pragma unroll
                    for (int r = 0; r < 8; ++r) sum += part[r][g][u];
                    z[g] = sum;
                }
                float ig = sigf(z[0]);
                float fg = sigf(z[1]);
                float gg = tanhfast(z[2]);
                float og = sigf(z[3]);
                cst  = fg * cst + ig * gg;
                hcur = og * tanhfast(cst);
                float* hw = hbuf + ((size_t)((t + 1) & 1) * 64 + grp) * 256;
                unsigned hb32 = (__float_as_uint(hcur) & 0xFFFFFF00u)
                              | ((unsigned)(t + 1) & 0xFFu);
                coh_store_u32((unsigned*)(hw + col0), hb32);
            }
        }
        // fused maxpool3 stride3 SAME: window t' covers t in {3t'-1, 3t', 3t'+1}
        if (rg == 0) {
            pm = fmaxf(pm, hcur);
            if ((t % 3) == 1) {
                int tp = (t - 1) / 3;
                pooled[(((size_t)br * 32 + s) * TP + tp) * HID + col0] = pm;
                pm = -1e30f;
            }
        }
    }
    if (rg == 0)   // final window t'=341 covers t=1022,1023
        pooled[(((size_t)br * 32 + s) * TP + 341) * HID + col0] = pm;
}

// ---------------- LSTM layers 2/3 (input projection precomputed) -----------
__global__ __launch_bounds__(512, 2) void lstm23_kernel(
    const float* __restrict__ xz,      // [2][32][342][1024] (bias folded in)
    const int* __restrict__ x_len,
    const float* __restrict__ Wr_s, const float* __restrict__ Wr_c,
    float* __restrict__ hbuf,
    float* __restrict__ yout)          // [2][32][342][256]
{
    const int blk = blockIdx.x;
    const int q   = blk >> 6;
    const int grp = blk & 63;
    const int br  = grp >> 5;
    const int s   = grp & 31;
    const int tid = threadIdx.x;
    const int u   = tid & 63;
    const int rg  = tid >> 6;
    const int col0 = q * 64 + u;

    const float* Wr = br ? Wr_c : Wr_s;

    float w[4][32];
#pragma unroll
    for (int g = 0; g < 4; ++g)
#pragma unroll
        for (int k = 0; k < 32; ++k)
            w[g][k] = Wr[(size_t)(rg * 32 + k) * 1024 + g * 256 + col0];

    const int len = (x_len[s] + 2) / 3;   // seq_len after pool
    float cst = 0.f, hcur = 0.f;

    __shared__ float h_lds[256];
    __shared__ float part[8][4][64];

    const int q1 = (q + 1) & 3, q2 = (q + 2) & 3, q3 = (q + 3) & 3;

    for (int t = 0; t < TP; ++t) {
        const size_t row = ((size_t)br * 32 + s) * TP + t;
        if (t < len) {
            // wave0: issue xz loads before the poll (they overlap discovery)
            float xzv[4] = {0.f, 0.f, 0.f, 0.f};
            if (rg == 0) {
#pragma unroll
                for (int g = 0; g < 4; ++g)
                    xzv[g] = xz[row * 1024 + g * 256 + col0];
                const float* hb = hbuf + ((size_t)(t & 1) * 64 + grp) * 256;
                float r0, r1, r2;
                poll3(hb + q1 * 64 + u, hb + q2 * 64 + u, hb + q3 * 64 + u,
                      (unsigned)t & 0xFFu, r0, r1, r2);
                h_lds[q1 * 64 + u] = untag(r0);
                h_lds[q2 * 64 + u] = untag(r1);
                h_lds[q3 * 64 + u] = untag(r2);
                h_lds[q  * 64 + u] = hcur;
            }
            __syncthreads();

            f32x4 hv[8];
            const f32x4* hp = (const f32x4*)&h_lds[rg * 32];
#pragma unroll
            for (int i = 0; i < 8; ++i) hv[i] = hp[i];
            float acc[4] = {0.f, 0.f, 0.f, 0.f};
#pragma unroll
            for (int i = 0; i < 8; ++i) {
#pragma unroll
                for (int jj = 0; jj < 4; ++jj) {
                    float hh = hv[i][jj];
#pragma unroll
                    for (int g = 0; g < 4; ++g)
                        acc[g] += hh * w[g][i * 4 + jj];
                }
            }
#pragma unroll
            for (int g = 0; g < 4; ++g) part[rg][g][u] = acc[g];
            __syncthreads();

            if (rg == 0) {
                float z[4];
#pragma unroll
                for (int g = 0; g < 4; ++g) {
                    float sum = xzv[g];
#pragma unroll
                    for (int r = 0; r < 8; ++r) sum += part[r][g][u];
                    z[g] = sum;
                }
                float ig = sigf(z[0]);
                float fg = sigf(z[1]);
                float gg = tanhfast(z[2]);
                float og = sigf(z[3]);
                cst  = fg * cst + ig * gg;
                hcur = og * tanhfast(cst);
                float* hw = hbuf + ((size_t)((t + 1) & 1) * 64 + grp) * 256;
                unsigned hb32 = (__float_as_uint(hcur) & 0xFFFFFF00u)
                              | ((unsigned)(t + 1) & 0xFFu);
                coh_store_u32((unsigned*)(hw + col0), hb32);
            }
        }
        if (rg == 0)
            yout[row * HID + col0] = hcur;   // carried value when masked
    }
}

// ---------------- xz = A @ Wk + b (per-branch weights) ---------------------
// A: (21888, 256) rows 0..10943 branch s, 10944.. branch c. out: (21888, 1024)
__global__ __launch_bounds__(256) void gemm_xz(
    const float* __restrict__ A,
    const float* __restrict__ Ws, const float* __restrict__ Wc,
    const float* __restrict__ bs, const float* __restrict__ bc,
    float* __restrict__ out)
{
    __shared__ float As[32][68];    // [k][m], padded
    __shared__ float Bs[32][132];   // [k][n], padded
    const int tid = threadIdx.x;
    const int bx = blockIdx.x, by = blockIdx.y;   // 8 x 342
    const int row0 = by * 64, col0 = bx * 128;
    const int br = (by >= 171);
    const float* W    = br ? Wc : Ws;
    const float* bias = br ? bc : bs;
    const int tx = tid & 15, ty = tid >> 4;

    float acc[4][8];
#pragma unroll
    for (int i = 0; i < 4; ++i)
#pragma unroll
        for (int j = 0; j < 8; ++j) acc[i][j] = 0.f;

    for (int k0 = 0; k0 < 256; k0 += 32) {
#pragma unroll
        for (int i = 0; i < 2; ++i) {              // A tile 64x32, store transposed
            int c = tid * 2 + i;
            int r = c >> 3, kv = c & 7;
            float4 v = *(const float4*)(A + (size_t)(row0 + r) * 256 + k0 + kv * 4);
            As[kv * 4 + 0][r] = v.x; As[kv * 4 + 1][r] = v.y;
            As[kv * 4 + 2][r] = v.z; As[kv * 4 + 3][r] = v.w;
        }
#pragma unroll
        for (int i = 0; i < 4; ++i) {              // B tile 32x128
            int c = tid + i * 256;
            int kr = c >> 5, nv = c & 31;
            *(float4*)&Bs[kr][nv * 4] =
                *(const float4*)(W + (size_t)(k0 + kr) * 1024 + col0 + nv * 4);
        }
        __syncthreads();
#pragma unroll
        for (int k = 0; k < 32; ++k) {
            float4 a  = *(const float4*)&As[k][ty * 4];
            float4 b0 = *(const float4*)&Bs[k][tx * 8];
            float4 b1 = *(const float4*)&Bs[k][tx * 8 + 4];
            float av[4] = {a.x, a.y, a.z, a.w};
            float bv[8] = {b0.x, b0.y, b0.z, b0.w, b1.x, b1.y, b1.z, b1.w};
#pragma unroll
            for (int i = 0; i < 4; ++i)
#pragma unroll
                for (int j = 0; j < 8; ++j)
                    acc[i][j] += av[i] * bv[j];
        }
        __syncthreads();
    }
    float bv[8];
#pragma unroll
    for (int j = 0; j < 8; ++j) bv[j] = bias[col0 + tx * 8 + j];
#pragma unroll
    for (int i = 0; i < 4; ++i) {
        int r = row0 + ty * 4 + i;
        float4 o0 = {acc[i][0] + bv[0], acc[i][1] + bv[1], acc[i][2] + bv[2], acc[i][3] + bv[3]};
        float4 o1 = {acc[i][4] + bv[4], acc[i][5] + bv[5], acc[i][6] + bv[6], acc[i][7] + bv[7]};
        float* po = out + (size_t)r * 1024 + col0 + tx * 8;
        *(float4*)(po)     = o0;
        *(float4*)(po + 4) = o1;
    }
}

// ---------------- CTC projection -------------------------------------------
__global__ __launch_bounds__(256) void ctc_kernel(
    const float* __restrict__ Y,      // (21888, 256)
    const float* __restrict__ Wct,    // (256, 30)
    const float* __restrict__ bct,    // (30)
    float* __restrict__ dout)
{
    __shared__ float wl[256 * 30];
    __shared__ float yl[8][257];
    const int tid = threadIdx.x;
    const int row0 = blockIdx.x * 8;

    for (int i = tid; i < 7680; i += 256) wl[i] = Wct[i];
#pragma unroll
    for (int i = 0; i < 8; ++i) {
        int c = tid + i * 256;
        int r = c >> 8, k = c & 255;
        yl[r][k] = Y[(size_t)(row0 + r) * 256 + k];
    }
    __syncthreads();

    const int v = tid & 31, r = tid >> 5;
    if (v < 30) {
        float acc = bct[v];
#pragma unroll 8
        for (int k = 0; k < 256; ++k) acc += yl[r][k] * wl[k * 30 + v];
        int gr = row0 + r;
        int br = gr / 10944;
        int rr = gr - br * 10944;
        dout[(br ? 328352 : 0) + (size_t)rr * 30 + v] = acc;
    }
}

// ---------------- lens + close flags ----------------------------------------
__global__ __launch_bounds__(256) void finalize_kernel(
    const int* __restrict__ x_len, float* __restrict__ dout)
{
    const int b = blockIdx.x, tid = threadIdx.x;
    const float* cs = dout + (size_t)b * 10260;
    const float* cc = dout + 328352 + (size_t)b * 10260;
    __shared__ int flag;
    if (tid == 0) flag = 1;
    __syncthreads();
    bool ok = true;
    for (int i = tid; i < 10260; i += 256)
        ok &= (fabsf(cs[i] - cc[i]) < 1e-5f);
    if (!ok) atomicAnd(&flag, 0);
    __syncthreads();
    if (tid == 0) {
        float L = (float)((x_len[b] + 2) / 3);
        dout[328320 + b] = L;          // len_s
        dout[656672 + b] = L;          // len_c
        dout[656704 + b] = flag ? 1.0f : 0.0f;  // close
    }
}

// ---------------------------------------------------------------------------
extern "C" void kernel_launch(void* const* d_in, const int* in_sizes, int n_in,
                              void* d_out, int out_size, void* d_ws, size_t ws_size,
                              hipStream_t stream)
{
    (void)in_sizes; (void)n_in; (void)out_size;
    const float* x     = (const float*)d_in[0];
    const int*   x_len = (const int*)  d_in[1];
    const float* ws0_k = (const float*)d_in[2];
    const float* ws0_r = (const float*)d_in[3];
    const float* ws0_b = (const float*)d_in[4];
    const float* ws1_k = (const float*)d_in[5];
    const float* ws1_r = (const float*)d_in[6];
    const float* ws1_b = (const float*)d_in[7];
    const float* wc0_k = (const float*)d_in[8];
    const float* wc0_r = (const float*)d_in[9];
    const float* wc0_b = (const float*)d_in[10];
    const float* wc1_k = (const float*)d_in[11];
    const float* wc1_r = (const float*)d_in[12];
    const float* wc1_b = (const float*)d_in[13];
    const float* ctc_w = (const float*)d_in[14];
    const float* ctc_b = (const float*)d_in[15];
    float* out = (float*)d_out;
    char*  ws  = (char*)d_ws;

    // workspace layout
    const size_t h_bytes  = 3ull * 2 * 64 * 256 * sizeof(float);      // 393216
    const size_t off_b0   = h_bytes;
    const size_t b0_bytes = 2ull * 32 * 342 * 256 * sizeof(float);    // 22.4 MB (pooled/ys2/ys3)
    const size_t off_b1   = off_b0 + b0_bytes;
    const size_t b1_bytes = 2ull * 32 * 342 * 1024 * sizeof(float);   // 89.7 MB (xz)
    if (ws_size < off_b1 + b1_bytes) return;   // need ~112 MB

    float* h1 = (float*)ws;
    float* h2 = h1 + 2 * 64 * 256;
    float* h3 = h2 + 2 * 64 * 256;
    float* buf0 = (float*)(ws + off_b0);
    float* buf1 = (float*)(ws + off_b1);

    // zero h double-buffers (h=0, tag=0 for t=0) — fresh every launch/replay
    hipMemsetAsync(ws, 0, h_bytes, stream);

    // LSTM1 + fused maxpool -> buf0 = pooled
    lstm1_kernel<<<256, 512, 0, stream>>>(x, x_len, ws0_k, ws0_r, ws0_b,
                                          wc0_k, wc0_r, wc0_b, h1, buf0);
    // xz2 = pooled @ Wk1 + b1 -> buf1
    gemm_xz<<<dim3(8, 342), 256, 0, stream>>>(buf0, ws1_k, wc1_k, ws1_b, wc1_b, buf1);
    // LSTM2 -> buf0 = ys2
    lstm23_kernel<<<256, 512, 0, stream>>>(buf1, x_len, ws1_r, wc1_r, h2, buf0);
    // xz3 = ys2 @ Wk1 + b1 -> buf1
    gemm_xz<<<dim3(8, 342), 256, 0, stream>>>(buf0, ws1_k, wc1_k, ws1_b, wc1_b, buf1);
    // LSTM3 -> buf0 = ys3
    lstm23_kernel<<<256, 512, 0, stream>>>(buf1, x_len, ws1_r, wc1_r, h3, buf0);
    // CTC projection -> d_out ctc regions
    ctc_kernel<<<2736, 256, 0, stream>>>(buf0, ctc_w, ctc_b, out);
    // lens + close
    finalize_kernel<<<32, 256, 0, stream>>>(x_len, out);
}

// Round 10
// 2145.078 us; speedup vs baseline: 1.4856x; 1.0748x over previous
//
#include <hip/hip_runtime.h>

// ---------------------------------------------------------------------------
// 2-branch LSTM-CTC transcriber for MI355X.  B=32, T=1024, F=40, H=256.
//
// Round-10 changes vs round-9 (protocol unchanged, serial-path shaving):
//  * part[] LDS layout [r][u][4] (f32x4): wave0 reduce = 8 ds_read_b128
//    instead of 32 ds_read_b32; part write = 1 ds_write_b128.
//  * poll3 deepened to a 3-set (a/b/c) pipeline with s_waitcnt vmcnt(6):
//    poll period ~RT/3, discovery latency -~100 cyc.
//  * Input prefetch: lstm1 waves 3..7 load x(t+1) during phase-2 (hides
//    first-touch HBM misses that exceed the poll window); lstm23 wave0
//    prefetches xz(t+1) immediately after publishing h(t+1).
//  * (kept from r9: single-poller wave0 + LDS broadcast, tag-in-mantissa
//    h exchange via LLC sc0+sc1, 2 barriers/step, fused maxpool.)
// ---------------------------------------------------------------------------

#define HID 256
#define TT  1024
#define TP  342
#define FF  40

typedef float f32x4 __attribute__((ext_vector_type(4)));

__device__ __forceinline__ float sigf(float x)     { return 1.0f / (1.0f + __expf(-x)); }
__device__ __forceinline__ float tanhfast(float x) { return 1.0f - 2.0f / (__expf(2.0f * x) + 1.0f); }

__device__ __forceinline__ void coh_store_u32(unsigned* p, unsigned v) {
    asm volatile("global_store_dword %0, %1, off sc0 sc1"
                 :: "v"(p), "v"(v) : "memory");
}
__device__ __forceinline__ float untag(float v) {
    return __uint_as_float(__float_as_uint(v) & 0xFFFFFF00u);
}

// 3-deep pipelined poll on three lane-addressed dwords (LLC-coherent).
// Invariant at loop head: 6 loads outstanding (two older sets); issue the
// third set, then vmcnt(6) completes exactly the oldest set (in-order
// retirement). Tag monotonicity (each dword written once per step epoch)
// makes returning the witnessed set safe.
__device__ __forceinline__ void poll3(const float* p0, const float* p1, const float* p2,
                                      unsigned tag, float& r0, float& r1, float& r2) {
    float a0, a1, a2, b0, b1, b2, c0, c1, c2;
    unsigned t0, t1;
    asm volatile(
        "global_load_dword %[a0], %[p0], off sc0 sc1\n\t"
        "global_load_dword %[a1], %[p1], off sc0 sc1\n\t"
        "global_load_dword %[a2], %[p2], off sc0 sc1\n\t"
        "global_load_dword %[b0], %[p0], off sc0 sc1\n\t"
        "global_load_dword %[b1], %[p1], off sc0 sc1\n\t"
        "global_load_dword %[b2], %[p2], off sc0 sc1\n\t"
        "1:\n\t"
        "global_load_dword %[c0], %[p0], off sc0 sc1\n\t"
        "global_load_dword %[c1], %[p1], off sc0 sc1\n\t"
        "global_load_dword %[c2], %[p2], off sc0 sc1\n\t"
        "s_waitcnt vmcnt(6)\n\t"                  // set a complete
        "v_xor_b32 %[t0], %[a0], %[tag]\n\t"
        "v_xor_b32 %[t1], %[a1], %[tag]\n\t"
        "v_or_b32 %[t0], %[t0], %[t1]\n\t"
        "v_xor_b32 %[t1], %[a2], %[tag]\n\t"
        "v_or_b32 %[t0], %[t0], %[t1]\n\t"
        "v_and_b32 %[t0], 0xff, %[t0]\n\t"
        "v_cmp_ne_u32 vcc, 0, %[t0]\n\t"
        "s_cbranch_vccz 2f\n\t"
        "global_load_dword %[a0], %[p0], off sc0 sc1\n\t"
        "global_load_dword %[a1], %[p1], off sc0 sc1\n\t"
        "global_load_dword %[a2], %[p2], off sc0 sc1\n\t"
        "s_waitcnt vmcnt(6)\n\t"                  // set b complete
        "v_xor_b32 %[t0], %[b0], %[tag]\n\t"
        "v_xor_b32 %[t1], %[b1], %[tag]\n\t"
        "v_or_b32 %[t0], %[t0], %[t1]\n\t"
        "v_xor_b32 %[t1], %[b2], %[tag]\n\t"
        "v_or_b32 %[t0], %[t0], %[t1]\n\t"
        "v_and_b32 %[t0], 0xff, %[t0]\n\t"
        "v_cmp_ne_u32 vcc, 0, %[t0]\n\t"
        "s_cbranch_vccz 3f\n\t"
        "global_load_dword %[b0], %[p0], off sc0 sc1\n\t"
        "global_load_dword %[b1], %[p1], off sc0 sc1\n\t"
        "global_load_dword %[b2], %[p2], off sc0 sc1\n\t"
        "s_waitcnt vmcnt(6)\n\t"                  // set c complete
        "v_xor_b32 %[t0], %[c0], %[tag]\n\t"
        "v_xor_b32 %[t1], %[c1], %[tag]\n\t"
        "v_or_b32 %[t0], %[t0], %[t1]\n\t"
        "v_xor_b32 %[t1], %[c2], %[tag]\n\t"
        "v_or_b32 %[t0], %[t0], %[t1]\n\t"
        "v_and_b32 %[t0], 0xff, %[t0]\n\t"
        "v_cmp_ne_u32 vcc, 0, %[t0]\n\t"
        "s_cbranch_vccnz 1b\n\t"
        "s_waitcnt vmcnt(0)\n\t"                  // c matched
        "v_mov_b32 %[a0], %[c0]\n\t"
        "v_mov_b32 %[a1], %[c1]\n\t"
        "v_mov_b32 %[a2], %[c2]\n\t"
        "s_branch 5f\n\t"
        "2:\n\t"
        "s_waitcnt vmcnt(0)\n\t"                  // a matched
        "s_branch 5f\n\t"
        "3:\n\t"
        "s_waitcnt vmcnt(0)\n\t"                  // b matched
        "v_mov_b32 %[a0], %[b0]\n\t"
        "v_mov_b32 %[a1], %[b1]\n\t"
        "v_mov_b32 %[a2], %[b2]\n\t"
        "5:\n\t"
        : [a0]"=&v"(a0), [a1]"=&v"(a1), [a2]"=&v"(a2),
          [b0]"=&v"(b0), [b1]"=&v"(b1), [b2]"=&v"(b2),
          [c0]"=&v"(c0), [c1]"=&v"(c1), [c2]"=&v"(c2),
          [t0]"=&v"(t0), [t1]"=&v"(t1)
        : [p0]"v"(p0), [p1]"v"(p1), [p2]"v"(p2), [tag]"v"(tag)
        : "vcc", "memory");
    r0 = a0; r1 = a1; r2 = a2;
}

// ---------------- LSTM layer 1 (input = clipped x, fused maxpool) ----------
__global__ __launch_bounds__(512, 2) void lstm1_kernel(
    const float* __restrict__ x, const int* __restrict__ x_len,
    const float* __restrict__ Wk_s, const float* __restrict__ Wr_s, const float* __restrict__ b_s,
    const float* __restrict__ Wk_c, const float* __restrict__ Wr_c, const float* __restrict__ b_c,
    float* __restrict__ hbuf,          // [2][64][256] (zeroed -> h=0, tag=0)
    float* __restrict__ pooled)        // [2][32][342][256]
{
    const int blk = blockIdx.x;        // 0..255
    const int q   = blk >> 6;          // quarter 0..3
    const int grp = blk & 63;          // (branch, sample)
    const int br  = grp >> 5;
    const int s   = grp & 31;
    const int tid = threadIdx.x;
    const int u   = tid & 63;          // unit within quarter
    const int rg  = tid >> 6;          // row-group 0..7 (32 h-rows each)
    const int col0 = q * 64 + u;       // output unit index within H

    const float* Wk = br ? Wk_c : Wk_s;
    const float* Wr = br ? Wr_c : Wr_s;
    const float* bb = br ? b_c  : b_s;

    // Recurrent weight slice: w[g][k] = Wr[rg*32+k][g*256+col0]
    float w[4][32];
#pragma unroll
    for (int g = 0; g < 4; ++g)
#pragma unroll
        for (int k = 0; k < 32; ++k)
            w[g][k] = Wr[(size_t)(rg * 32 + k) * 1024 + g * 256 + col0];

    // Input-kernel slice on waves 3..7 (wave0 is the poller):
    float wk[4][8];
    if (rg >= 3) {
#pragma unroll
        for (int g = 0; g < 4; ++g)
#pragma unroll
            for (int j = 0; j < 8; ++j)
                wk[g][j] = Wk[(size_t)((rg - 3) * 8 + j) * 1024 + g * 256 + col0];
    }

    f32x4 bias = {0.f, 0.f, 0.f, 0.f};
    if (rg == 0) {
#pragma unroll
        for (int g = 0; g < 4; ++g) bias[g] = bb[g * 256 + col0];
    }

    const int len = x_len[s];
    float cst = 0.f, hcur = 0.f, pm = -1e30f;

    __shared__ float h_lds[256];
    __shared__ f32x4 part[8][64];      // [r][u] -> ds_*_b128

    const int q1 = (q + 1) & 3, q2 = (q + 2) & 3, q3 = (q + 3) & 3;

    // prefetch x row for t=0 (len >= 1 guaranteed)
    float xv[8];
    if (rg >= 3) {
        const float* xr = x + (size_t)s * TT * FF + (rg - 3) * 8;
#pragma unroll
        for (int j = 0; j < 8; ++j) xv[j] = xr[j];
    }

    for (int t = 0; t < TT; ++t) {
        if (t < len) {
            // ---- phase 1: wave0 polls remote quarters -> LDS broadcast;
            //      waves 3..7 fold in the (prefetched) x contribution.
            float acc[4] = {0.f, 0.f, 0.f, 0.f};
            if (rg >= 3) {
#pragma unroll
                for (int j = 0; j < 8; ++j) {
                    float v = fminf(fmaxf(xv[j], -3.f), 3.f);   // clip(x,-3,3)
#pragma unroll
                    for (int g = 0; g < 4; ++g) acc[g] += v * wk[g][j];
                }
            }
            if (rg == 0) {
                const float* hb = hbuf + ((size_t)(t & 1) * 64 + grp) * 256;
                float r0, r1, r2;
                poll3(hb + q1 * 64 + u, hb + q2 * 64 + u, hb + q3 * 64 + u,
                      (unsigned)t & 0xFFu, r0, r1, r2);
                h_lds[q1 * 64 + u] = untag(r0);
                h_lds[q2 * 64 + u] = untag(r1);
                h_lds[q3 * 64 + u] = untag(r2);
                h_lds[q  * 64 + u] = hcur;            // own quarter from regs
            }
            __syncthreads();                          // h_lds ready

            // ---- phase 2: all waves FMA from LDS h
            f32x4 hv[8];
            const f32x4* hp = (const f32x4*)&h_lds[rg * 32];
#pragma unroll
            for (int i = 0; i < 8; ++i) hv[i] = hp[i];
#pragma unroll
            for (int i = 0; i < 8; ++i) {
#pragma unroll
                for (int jj = 0; jj < 4; ++jj) {
                    float hh = hv[i][jj];
#pragma unroll
                    for (int g = 0; g < 4; ++g)
                        acc[g] += hh * w[g][i * 4 + jj];
                }
            }
            f32x4 pv = {acc[0], acc[1], acc[2], acc[3]};
            part[rg][u] = pv;                         // ds_write_b128

            // prefetch x row for t+1 while waiting at the barrier
            if (rg >= 3 && t + 1 < len) {
                const float* xr = x + ((size_t)s * TT + t + 1) * FF + (rg - 3) * 8;
#pragma unroll
                for (int j = 0; j < 8; ++j) xv[j] = xr[j];
            }
            __syncthreads();                          // parts ready

            // ---- phase 3: wave0 reduce (b128 reads) + gates + publish
            if (rg == 0) {
                f32x4 zv = bias;
#pragma unroll
                for (int r = 0; r < 8; ++r) zv += part[r][u];   // ds_read_b128
                float ig = sigf(zv[0]);
                float fg = sigf(zv[1]);
                float gg = tanhfast(zv[2]);
                float og = sigf(zv[3]);
                cst  = fg * cst + ig * gg;
                hcur = og * tanhfast(cst);
                float* hw = hbuf + ((size_t)((t + 1) & 1) * 64 + grp) * 256;
                unsigned hb32 = (__float_as_uint(hcur) & 0xFFFFFF00u)
                              | ((unsigned)(t + 1) & 0xFFu);
                coh_store_u32((unsigned*)(hw + col0), hb32);
            }
        }
        // fused maxpool3 stride3 SAME: window t' covers t in {3t'-1, 3t', 3t'+1}
        if (rg == 0) {
            pm = fmaxf(pm, hcur);
            if ((t % 3) == 1) {
                int tp = (t - 1) / 3;
                pooled[(((size_t)br * 32 + s) * TP + tp) * HID + col0] = pm;
                pm = -1e30f;
            }
        }
    }
    if (rg == 0)   // final window t'=341 covers t=1022,1023
        pooled[(((size_t)br * 32 + s) * TP + 341) * HID + col0] = pm;
}

// ---------------- LSTM layers 2/3 (input projection precomputed) -----------
__global__ __launch_bounds__(512, 2) void lstm23_kernel(
    const float* __restrict__ xz,      // [2][32][342][1024] (bias folded in)
    const int* __restrict__ x_len,
    const float* __restrict__ Wr_s, const float* __restrict__ Wr_c,
    float* __restrict__ hbuf,
    float* __restrict__ yout)          // [2][32][342][256]
{
    const int blk = blockIdx.x;
    const int q   = blk >> 6;
    const int grp = blk & 63;
    const int br  = grp >> 5;
    const int s   = grp & 31;
    const int tid = threadIdx.x;
    const int u   = tid & 63;
    const int rg  = tid >> 6;
    const int col0 = q * 64 + u;

    const float* Wr = br ? Wr_c : Wr_s;

    float w[4][32];
#pragma unroll
    for (int g = 0; g < 4; ++g)
#pragma unroll
        for (int k = 0; k < 32; ++k)
            w[g][k] = Wr[(size_t)(rg * 32 + k) * 1024 + g * 256 + col0];

    const int len = (x_len[s] + 2) / 3;   // seq_len after pool
    float cst = 0.f, hcur = 0.f;

    __shared__ float h_lds[256];
    __shared__ f32x4 part[8][64];

    const int q1 = (q + 1) & 3, q2 = (q + 2) & 3, q3 = (q + 3) & 3;
    const size_t row0 = ((size_t)br * 32 + s) * TP;

    // prefetch xz row for t=0 (len >= 1 guaranteed)
    float xzn[4];
    if (rg == 0) {
#pragma unroll
        for (int g = 0; g < 4; ++g)
            xzn[g] = xz[row0 * 1024 + g * 256 + col0];
    }

    for (int t = 0; t < TP; ++t) {
        const size_t row = row0 + t;
        if (t < len) {
            float xzv[4];
            if (rg == 0) {
#pragma unroll
                for (int g = 0; g < 4; ++g) xzv[g] = xzn[g];   // consume prefetch
                const float* hb = hbuf + ((size_t)(t & 1) * 64 + grp) * 256;
                float r0, r1, r2;
                poll3(hb + q1 * 64 + u, hb + q2 * 64 + u, hb + q3 * 64 + u,
                      (unsigned)t & 0xFFu, r0, r1, r2);
                h_lds[q1 * 64 + u] = untag(r0);
                h_lds[q2 * 64 + u] = untag(r1);
                h_lds[q3 * 64 + u] = untag(r2);
                h_lds[q  * 64 + u] = hcur;
            }
            __syncthreads();

            f32x4 hv[8];
            const f32x4* hp = (const f32x4*)&h_lds[rg * 32];
#pragma unroll
            for (int i = 0; i < 8; ++i) hv[i] = hp[i];
            float acc[4] = {0.f, 0.f, 0.f, 0.f};
#pragma unroll
            for (int i = 0; i < 8; ++i) {
#pragma unroll
                for (int jj = 0; jj < 4; ++jj) {
                    float hh = hv[i][jj];
#pragma unroll
                    for (int g = 0; g < 4; ++g)
                        acc[g] += hh * w[g][i * 4 + jj];
                }
            }
            f32x4 pv = {acc[0], acc[1], acc[2], acc[3]};
            part[rg][u] = pv;
            __syncthreads();

            if (rg == 0) {
                f32x4 zv = {xzv[0], xzv[1], xzv[2], xzv[3]};
#pragma unroll
                for (int r = 0; r < 8; ++r) zv += part[r][u];
                float ig = sigf(zv[0]);
                float fg = sigf(zv[1]);
                float gg = tanhfast(zv[2]);
                float og = sigf(zv[3]);
                cst  = fg * cst + ig * gg;
                hcur = og * tanhfast(cst);
                float* hw = hbuf + ((size_t)((t + 1) & 1) * 64 + grp) * 256;
                unsigned hb32 = (__float_as_uint(hcur) & 0xFFFFFF00u)
                              | ((unsigned)(t + 1) & 0xFFu);
                coh_store_u32((unsigned*)(hw + col0), hb32);
                // prefetch xz for t+1 (hides HBM latency under next poll)
                if (t + 1 < len) {
#pragma unroll
                    for (int g = 0; g < 4; ++g)
                        xzn[g] = xz[(row + 1) * 1024 + g * 256 + col0];
                }
            }
        }
        if (rg == 0)
            yout[row * HID + col0] = hcur;   // carried value when masked
    }
}

// ---------------- xz = A @ Wk + b (per-branch weights) ---------------------
// A: (21888, 256) rows 0..10943 branch s, 10944.. branch c. out: (21888, 1024)
__global__ __launch_bounds__(256) void gemm_xz(
    const float* __restrict__ A,
    const float* __restrict__ Ws, const float* __restrict__ Wc,
    const float* __restrict__ bs, const float* __restrict__ bc,
    float* __restrict__ out)
{
    __shared__ float As[32][68];    // [k][m], padded
    __shared__ float Bs[32][132];   // [k][n], padded
    const int tid = threadIdx.x;
    const int bx = blockIdx.x, by = blockIdx.y;   // 8 x 342
    const int row0 = by * 64, col0 = bx * 128;
    const int br = (by >= 171);
    const float* W    = br ? Wc : Ws;
    const float* bias = br ? bc : bs;
    const int tx = tid & 15, ty = tid >> 4;

    float acc[4][8];
#pragma unroll
    for (int i = 0; i < 4; ++i)
#pragma unroll
        for (int j = 0; j < 8; ++j) acc[i][j] = 0.f;

    for (int k0 = 0; k0 < 256; k0 += 32) {
#pragma unroll
        for (int i = 0; i < 2; ++i) {              // A tile 64x32, store transposed
            int c = tid * 2 + i;
            int r = c >> 3, kv = c & 7;
            float4 v = *(const float4*)(A + (size_t)(row0 + r) * 256 + k0 + kv * 4);
            As[kv * 4 + 0][r] = v.x; As[kv * 4 + 1][r] = v.y;
            As[kv * 4 + 2][r] = v.z; As[kv * 4 + 3][r] = v.w;
        }
#pragma unroll
        for (int i = 0; i < 4; ++i) {              // B tile 32x128
            int c = tid + i * 256;
            int kr = c >> 5, nv = c & 31;
            *(float4*)&Bs[kr][nv * 4] =
                *(const float4*)(W + (size_t)(k0 + kr) * 1024 + col0 + nv * 4);
        }
        __syncthreads();
#pragma unroll
        for (int k = 0; k < 32; ++k) {
            float4 a  = *(const float4*)&As[k][ty * 4];
            float4 b0 = *(const float4*)&Bs[k][tx * 8];
            float4 b1 = *(const float4*)&Bs[k][tx * 8 + 4];
            float av[4] = {a.x, a.y, a.z, a.w};
            float bv[8] = {b0.x, b0.y, b0.z, b0.w, b1.x, b1.y, b1.z, b1.w};
#pragma unroll
            for (int i = 0; i < 4; ++i)
#pragma unroll
                for (int j = 0; j < 8; ++j)
                    acc[i][j] += av[i] * bv[j];
        }
        __syncthreads();
    }
    float bv[8];
#pragma unroll
    for (int j = 0; j < 8; ++j) bv[j] = bias[col0 + tx * 8 + j];
#pragma unroll
    for (int i = 0; i < 4; ++i) {
        int r = row0 + ty * 4 + i;
        float4 o0 = {acc[i][0] + bv[0], acc[i][1] + bv[1], acc[i][2] + bv[2], acc[i][3] + bv[3]};
        float4 o1 = {acc[i][4] + bv[4], acc[i][5] + bv[5], acc[i][6] + bv[6], acc[i][7] + bv[7]};
        float* po = out + (size_t)r * 1024 + col0 + tx * 8;
        *(float4*)(po)     = o0;
        *(float4*)(po + 4) = o1;
    }
}

// ---------------- CTC projection -------------------------------------------
__global__ __launch_bounds__(256) void ctc_kernel(
    const float* __restrict__ Y,      // (21888, 256)
    const float* __restrict__ Wct,    // (256, 30)
    const float* __restrict__ bct,    // (30)
    float* __restrict__ dout)
{
    __shared__ float wl[256 * 30];
    __shared__ float yl[8][257];
    const int tid = threadIdx.x;
    const int row0 = blockIdx.x * 8;

    for (int i = tid; i < 7680; i += 256) wl[i] = Wct[i];
#pragma unroll
    for (int i = 0; i < 8; ++i) {
        int c = tid + i * 256;
        int r = c >> 8, k = c & 255;
        yl[r][k] = Y[(size_t)(row0 + r) * 256 + k];
    }
    __syncthreads();

    const int v = tid & 31, r = tid >> 5;
    if (v < 30) {
        float acc = bct[v];
#pragma unroll 8
        for (int k = 0; k < 256; ++k) acc += yl[r][k] * wl[k * 30 + v];
        int gr = row0 + r;
        int br = gr / 10944;
        int rr = gr - br * 10944;
        dout[(br ? 328352 : 0) + (size_t)rr * 30 + v] = acc;
    }
}

// ---------------- lens + close flags ----------------------------------------
__global__ __launch_bounds__(256) void finalize_kernel(
    const int* __restrict__ x_len, float* __restrict__ dout)
{
    const int b = blockIdx.x, tid = threadIdx.x;
    const float* cs = dout + (size_t)b * 10260;
    const float* cc = dout + 328352 + (size_t)b * 10260;
    __shared__ int flag;
    if (tid == 0) flag = 1;
    __syncthreads();
    bool ok = true;
    for (int i = tid; i < 10260; i += 256)
        ok &= (fabsf(cs[i] - cc[i]) < 1e-5f);
    if (!ok) atomicAnd(&flag, 0);
    __syncthreads();
    if (tid == 0) {
        float L = (float)((x_len[b] + 2) / 3);
        dout[328320 + b] = L;          // len_s
        dout[656672 + b] = L;          // len_c
        dout[656704 + b] = flag ? 1.0f : 0.0f;  // close
    }
}

// ---------------------------------------------------------------------------
extern "C" void kernel_launch(void* const* d_in, const int* in_sizes, int n_in,
                              void* d_out, int out_size, void* d_ws, size_t ws_size,
                              hipStream_t stream)
{
    (void)in_sizes; (void)n_in; (void)out_size;
    const float* x     = (const float*)d_in[0];
    const int*   x_len = (const int*)  d_in[1];
    const float* ws0_k = (const float*)d_in[2];
    const float* ws0_r = (const float*)d_in[3];
    const float* ws0_b = (const float*)d_in[4];
    const float* ws1_k = (const float*)d_in[5];
    const float* ws1_r = (const float*)d_in[6];
    const float* ws1_b = (const float*)d_in[7];
    const float* wc0_k = (const float*)d_in[8];
    const float* wc0_r = (const float*)d_in[9];
    const float* wc0_b = (const float*)d_in[10];
    const float* wc1_k = (const float*)d_in[11];
    const float* wc1_r = (const float*)d_in[12];
    const float* wc1_b = (const float*)d_in[13];
    const float* ctc_w = (const float*)d_in[14];
    const float* ctc_b = (const float*)d_in[15];
    float* out = (float*)d_out;
    char*  ws  = (char*)d_ws;

    // workspace layout
    const size_t h_bytes  = 3ull * 2 * 64 * 256 * sizeof(float);      // 393216
    const size_t off_b0   = h_bytes;
    const size_t b0_bytes = 2ull * 32 * 342 * 256 * sizeof(float);    // 22.4 MB (pooled/ys2/ys3)
    const size_t off_b1   = off_b0 + b0_bytes;
    const size_t b1_bytes = 2ull * 32 * 342 * 1024 * sizeof(float);   // 89.7 MB (xz)
    if (ws_size < off_b1 + b1_bytes) return;   // need ~112 MB

    float* h1 = (float*)ws;
    float* h2 = h1 + 2 * 64 * 256;
    float* h3 = h2 + 2 * 64 * 256;
    float* buf0 = (float*)(ws + off_b0);
    float* buf1 = (float*)(ws + off_b1);

    // zero h double-buffers (h=0, tag=0 for t=0) — fresh every launch/replay
    hipMemsetAsync(ws, 0, h_bytes, stream);

    // LSTM1 + fused maxpool -> buf0 = pooled
    lstm1_kernel<<<256, 512, 0, stream>>>(x, x_len, ws0_k, ws0_r, ws0_b,
                                          wc0_k, wc0_r, wc0_b, h1, buf0);
    // xz2 = pooled @ Wk1 + b1 -> buf1
    gemm_xz<<<dim3(8, 342), 256, 0, stream>>>(buf0, ws1_k, wc1_k, ws1_b, wc1_b, buf1);
    // LSTM2 -> buf0 = ys2
    lstm23_kernel<<<256, 512, 0, stream>>>(buf1, x_len, ws1_r, wc1_r, h2, buf0);
    // xz3 = ys2 @ Wk1 + b1 -> buf1
    gemm_xz<<<dim3(8, 342), 256, 0, stream>>>(buf0, ws1_k, wc1_k, ws1_b, wc1_b, buf1);
    // LSTM3 -> buf0 = ys3
    lstm23_kernel<<<256, 512, 0, stream>>>(buf1, x_len, ws1_r, wc1_r, h3, buf0);
    // CTC projection -> d_out ctc regions
    ctc_kernel<<<2736, 256, 0, stream>>>(buf0, ctc_w, ctc_b, out);
    // lens + close
    finalize_kernel<<<32, 256, 0, stream>>>(x_len, out);
}